// Round 1
// baseline (88.182 us; speedup 1.0000x reference)
//
#include <hip/hip_runtime.h>

#define XX 36
#define XY 10
#define ROW 396               // XX * (XY + 1)
#define ROWS_PER_BLK 8
#define BLK 256
#define ELEMS_PER_BLK (ROWS_PER_BLK * ROW)   // 3168
#define VEC4_PER_BLK (ELEMS_PER_BLK / 4)     // 792

__global__ __launch_bounds__(BLK)
void lorenz96_fs_kernel(const float* __restrict__ u,
                        const float* __restrict__ param,
                        float* __restrict__ out,
                        int nrows) {
    __shared__ float s[ELEMS_PER_BLK];

    const float F = param[0];
    const float h = param[1];
    const float c = param[2];
    const float b = param[3];
    const float hc_over_xy = h * c * (1.0f / (float)XY);
    const float h_over_xy  = h * (1.0f / (float)XY);

    const long long base = (long long)blockIdx.x * ELEMS_PER_BLK;

    // ---- stage 8 rows into LDS, coalesced float4 ----
    const float4* __restrict__ in4 = (const float4*)(u + base);
    float4* s4 = (float4*)s;
    #pragma unroll
    for (int idx = threadIdx.x; idx < VEC4_PER_BLK; idx += BLK) {
        s4[idx] = in4[idx];
    }
    __syncthreads();

    // ---- compute 3168 outputs ----
    float* __restrict__ o = out + base;
    for (int k = threadIdx.x; k < ELEMS_PER_BLK; k += BLK) {
        const int r    = k / ROW;
        const int cidx = k - r * ROW;
        const float* __restrict__ row = s + r * ROW;
        float val;
        if (cidx < XX) {
            // dx[i] = (x[i+1] - x[i-2]) * x[i-1] - x[i] + F - h*c*mean(y[i,:])
            const int i = cidx;
            const float xp1 = row[(i + 1) % XX];
            const float xm1 = row[(i + XX - 1) % XX];
            const float xm2 = row[(i + XX - 2) % XX];
            const float* __restrict__ yr = row + XX + i * XY;
            float sum = 0.0f;
            #pragma unroll
            for (int j = 0; j < XY; ++j) sum += yr[j];
            val = (xp1 - xm2) * xm1 - row[i] + F - hc_over_xy * sum;
        } else {
            // dy[i][j] = c*(-b*y[i,j+1]*(y[i,j+2]-y[i,j-1]) - y[i,j] + h/10*x[i])
            const int t = cidx - XX;
            const int i = t / XY;
            const int j = t - i * XY;
            const float* __restrict__ yr = row + XX + i * XY;
            const float yp1 = yr[(j + 1) % XY];
            const float yp2 = yr[(j + 2) % XY];
            const float ym1 = yr[(j + XY - 1) % XY];
            val = c * (-b * yp1 * (yp2 - ym1) - yr[j] + h_over_xy * row[i]);
        }
        o[k] = val;
    }
}

extern "C" void kernel_launch(void* const* d_in, const int* in_sizes, int n_in,
                              void* d_out, int out_size, void* d_ws, size_t ws_size,
                              hipStream_t stream) {
    // inputs: d_in[0] = t (int scalar, unused), d_in[1] = u (f32), d_in[2] = param (f32 x4)
    const float* u     = (const float*)d_in[1];
    const float* param = (const float*)d_in[2];
    float* out         = (float*)d_out;

    const int nrows = in_sizes[1] / ROW;          // 131072
    const int nblocks = nrows / ROWS_PER_BLK;     // 16384 (131072 % 8 == 0)

    lorenz96_fs_kernel<<<nblocks, BLK, 0, stream>>>(u, param, out, nrows);
}

// Round 2
// 84.690 us; speedup vs baseline: 1.0412x; 1.0412x over previous
//
#include <hip/hip_runtime.h>

#define XX 36
#define XY 10
#define ROW 396               // XX * (XY + 1)
#define RPB 16                // rows per block
#define BLK (RPB * XX)        // 576 threads = 9 waves
#define EPB (RPB * ROW)       // 6336 floats per block
#define V4  (EPB / 4)         // 1584 float4 per block

__global__ __launch_bounds__(BLK)
void lorenz96_fs_kernel(const float* __restrict__ u,
                        const float* __restrict__ param,
                        float* __restrict__ out) {
    __shared__ float s[EPB];
    const int tid = threadIdx.x;

    const float F = param[0];
    const float h = param[1];
    const float c = param[2];
    const float b = param[3];
    const float hc10 = h * c * 0.1f;   // h*c/XY
    const float h10  = h * 0.1f;       // h/XY

    const long long base = (long long)blockIdx.x * EPB;

    // ---- stage 16 rows into LDS, coalesced float4 ----
    const float4* __restrict__ in4 = (const float4*)(u + base);
    float4* s4 = (float4*)s;
    #pragma unroll
    for (int idx = tid; idx < V4; idx += BLK) s4[idx] = in4[idx];
    __syncthreads();

    // ---- one thread per (row, group): computes dx[i] + dy[i][0..9] ----
    const int r = tid / XX;            // 0..15  (single div per thread)
    const int i = tid - r * XX;        // 0..35
    const float* __restrict__ row = s + r * ROW;

    const int ip1 = (i + 1 < XX) ? i + 1 : i + 1 - XX;
    const int im1 = (i - 1 >= 0) ? i - 1 : i - 1 + XX;
    const int im2 = (i - 2 >= 0) ? i - 2 : i - 2 + XX;

    const float xi  = row[i];
    const float xp1 = row[ip1];
    const float xm1 = row[im1];
    const float xm2 = row[im2];

    float y[XY];
    const float* __restrict__ yr = row + XX + i * XY;
    #pragma unroll
    for (int j = 0; j < XY; ++j) y[j] = yr[j];

    float sum = 0.0f;
    #pragma unroll
    for (int j = 0; j < XY; ++j) sum += y[j];

    const float dx = (xp1 - xm2) * xm1 - xi + F - hc10 * sum;

    float dy[XY];
    const float cb  = c * b;
    const float add = h10 * xi;
    #pragma unroll
    for (int j = 0; j < XY; ++j) {
        const int jp1 = (j + 1) % XY;          // compile-time constants
        const int jp2 = (j + 2) % XY;
        const int jm1 = (j + XY - 1) % XY;
        dy[j] = c * (add - y[j]) - cb * y[jp1] * (y[jp2] - y[jm1]);
    }

    __syncthreads();

    // ---- write results back into the same LDS tile ----
    s[r * ROW + i] = dx;
    float* __restrict__ so = s + r * ROW + XX + i * XY;
    #pragma unroll
    for (int j = 0; j < XY; ++j) so[j] = dy[j];

    __syncthreads();

    // ---- coalesced float4 store of the whole tile ----
    float4* __restrict__ o4 = (float4*)(out + base);
    #pragma unroll
    for (int idx = tid; idx < V4; idx += BLK) o4[idx] = s4[idx];
}

extern "C" void kernel_launch(void* const* d_in, const int* in_sizes, int n_in,
                              void* d_out, int out_size, void* d_ws, size_t ws_size,
                              hipStream_t stream) {
    // inputs: d_in[0] = t (int scalar, unused), d_in[1] = u (f32), d_in[2] = param (f32 x4)
    const float* u     = (const float*)d_in[1];
    const float* param = (const float*)d_in[2];
    float* out         = (float*)d_out;

    const int nrows   = in_sizes[1] / ROW;     // 131072
    const int nblocks = nrows / RPB;           // 8192 (131072 % 16 == 0)

    lorenz96_fs_kernel<<<nblocks, BLK, 0, stream>>>(u, param, out);
}

// Round 3
// 77.025 us; speedup vs baseline: 1.1449x; 1.0995x over previous
//
#include <hip/hip_runtime.h>

#define XX 36
#define XY 10
#define ROW 396               // XX * (XY + 1)
#define RPB 4                 // rows per block
#define BLK 256               // 4 waves -> 8 blocks/CU = 32 waves/CU
#define EPB (RPB * ROW)       // 1584 floats
#define V4  (EPB / 4)         // 396 float4
#define NG  (RPB * XX)        // 144 compute groups

__global__ __launch_bounds__(BLK, 8)
void lorenz96_fs_kernel(const float* __restrict__ u,
                        const float* __restrict__ param,
                        float* __restrict__ out) {
    __shared__ float si[EPB];   // input tile
    __shared__ float so[EPB];   // output tile (separate -> one fewer barrier)
    const int tid = threadIdx.x;

    const float F = param[0];
    const float h = param[1];
    const float c = param[2];
    const float b = param[3];

    const long long base = (long long)blockIdx.x * EPB;

    // ---- stage 4 rows into LDS, coalesced float4 (396 = 256 + 140) ----
    const float4* __restrict__ in4 = (const float4*)(u + base);
    float4* si4 = (float4*)si;
    si4[tid] = in4[tid];
    if (tid < V4 - BLK) si4[tid + BLK] = in4[tid + BLK];
    __syncthreads();

    // ---- one thread per (row, group); results go straight to out-tile ----
    if (tid < NG) {
        const int r = tid / XX;            // 0..3
        const int i = tid - r * XX;        // 0..35
        const float* __restrict__ row  = si + r * ROW;
        float*       __restrict__ orow = so + r * ROW;

        const float xi  = row[i];
        const float xp1 = row[(i + 1 < XX) ? i + 1 : i + 1 - XX];
        const float xm1 = row[(i >= 1) ? i - 1 : i + XX - 1];
        const float xm2 = row[(i >= 2) ? i - 2 : i + XX - 2];

        float y[XY];
        const float* __restrict__ yr = row + XX + i * XY;
        #pragma unroll
        for (int j = 0; j < XY; ++j) y[j] = yr[j];

        float sum = 0.0f;
        #pragma unroll
        for (int j = 0; j < XY; ++j) sum += y[j];

        orow[i] = (xp1 - xm2) * xm1 - xi + F - (h * c * 0.1f) * sum;

        const float add = h * 0.1f * xi;
        const float cb  = c * b;
        float* __restrict__ oyr = orow + XX + i * XY;
        #pragma unroll
        for (int j = 0; j < XY; ++j) {
            const int jp1 = (j + 1) % XY;          // compile-time under unroll
            const int jp2 = (j + 2) % XY;
            const int jm1 = (j + XY - 1) % XY;
            oyr[j] = c * (add - y[j]) - cb * y[jp1] * (y[jp2] - y[jm1]);
        }
    }
    __syncthreads();

    // ---- coalesced float4 store of the output tile ----
    const float4* __restrict__ so4 = (const float4*)so;
    float4* __restrict__ o4 = (float4*)(out + base);
    o4[tid] = so4[tid];
    if (tid < V4 - BLK) o4[tid + BLK] = so4[tid + BLK];
}

extern "C" void kernel_launch(void* const* d_in, const int* in_sizes, int n_in,
                              void* d_out, int out_size, void* d_ws, size_t ws_size,
                              hipStream_t stream) {
    // inputs: d_in[0] = t (int scalar, unused), d_in[1] = u (f32), d_in[2] = param (f32 x4)
    const float* u     = (const float*)d_in[1];
    const float* param = (const float*)d_in[2];
    float* out         = (float*)d_out;

    const int nrows   = in_sizes[1] / ROW;     // 131072
    const int nblocks = nrows / RPB;           // 32768

    lorenz96_fs_kernel<<<nblocks, BLK, 0, stream>>>(u, param, out);
}